// Round 11
// baseline (754.289 us; speedup 1.0000x reference)
//
#include <hip/hip_runtime.h>
#include <hip/hip_bf16.h>
#include <cstdint>

#define HID 128

typedef short s16x8 __attribute__((ext_vector_type(8)));
typedef float f32x4 __attribute__((ext_vector_type(4)));

static inline size_t align_up(size_t x, size_t a) { return (x + a - 1) & ~(a - 1); }

__device__ inline ushort f2bf(float f) {  // RNE bit-hack (cold paths)
  uint u = __float_as_uint(f);
  u += 0x7FFFu + ((u >> 16) & 1u);
  return (ushort)(u >> 16);
}
// Hot-path pair convert -> v_cvt_pk_bf16_f32 (RNE, same result)
__device__ inline uint pk2bf(float lo, float hi) {
  __hip_bfloat162 h = __float22bfloat162_rn(float2{lo, hi});
  return *reinterpret_cast<uint*>(&h);
}
__device__ inline float bf2f_lo(uint v) { return __uint_as_float(v << 16); }
__device__ inline float bf2f_hi(uint v) { return __uint_as_float(v & 0xFFFF0000u); }

// ---------------------------------------------------------------------------
// Edge dtype sniffer.
// ---------------------------------------------------------------------------
__global__ void detect_i64_kernel(const unsigned int* __restrict__ p, int nwords,
                                  int* __restrict__ flag) {
  __shared__ int any;
  if (threadIdx.x == 0) any = 0;
  __syncthreads();
  for (int i = threadIdx.x; i < 1024; i += blockDim.x) {
    int w = 2 * i + 1;
    if (w < nwords && p[w] != 0u) atomicOr(&any, 1);
  }
  __syncthreads();
  if (threadIdx.x == 0) *flag = (any == 0) ? 1 : 0;
}

// degree count: reads only the dst half of edge_index
__global__ void count_kernel(const void* __restrict__ ei, const int* __restrict__ flag,
                             int E, int* __restrict__ cnt) {
  int e = blockIdx.x * blockDim.x + threadIdx.x;
  if (e >= E) return;
  int d;
  if (*flag) d = (int)((const long long*)ei)[(size_t)E + e];
  else       d = ((const int*)ei)[(size_t)E + e];
  atomicAdd(&cnt[d], 1);
}

// ---------------------------------------------------------------------------
// Two-level exclusive scan over per-node counts -> CSR row offsets.
// dinv folded in.
// ---------------------------------------------------------------------------
__global__ __launch_bounds__(1024) void scan_local_kernel(const int* __restrict__ cnt,
    int* __restrict__ off, int* __restrict__ bsum, float* __restrict__ dinv, int N) {
  __shared__ int buf[1024];
  int tid = threadIdx.x;
  int i = blockIdx.x * 1024 + tid;
  int v = (i < N) ? cnt[i] : 0;
  buf[tid] = v;
  __syncthreads();
  #pragma unroll
  for (int s = 1; s < 1024; s <<= 1) {
    int t = (tid >= s) ? buf[tid - s] : 0;
    __syncthreads();
    buf[tid] += t;
    __syncthreads();
  }
  if (i < N) {
    off[i] = buf[tid] - v;
    dinv[i] = rsqrtf((float)(v + 1));  // +1 self-loop
  }
  if (tid == 1023) bsum[blockIdx.x] = buf[1023];
}

__global__ __launch_bounds__(128) void scan_bsum_kernel(const int* __restrict__ bsum, int nb,
    int* __restrict__ boff, int* __restrict__ offN) {
  __shared__ int b[128];
  int tid = threadIdx.x;
  int v = (tid < nb) ? bsum[tid] : 0;
  b[tid] = v;
  __syncthreads();
  #pragma unroll
  for (int s = 1; s < 128; s <<= 1) {
    int t = (tid >= s) ? b[tid - s] : 0;
    __syncthreads();
    b[tid] += t;
    __syncthreads();
  }
  if (tid < nb) boff[tid] = b[tid] - v;
  if (tid == 127) *offN = b[127];
}

__global__ void scan_add_kernel(int* __restrict__ off, const int* __restrict__ boff,
                                int* __restrict__ cursor, int N) {
  int i = blockIdx.x * blockDim.x + threadIdx.x;
  if (i >= N) return;
  int o = off[i] + boff[i >> 10];
  off[i] = o;
  cursor[i] = o;
}

// CSR fill: re-reads edge_index directly (L3-hot); one packed 8B scatter/edge.
__global__ void fill_kernel(const void* __restrict__ ei, const int* __restrict__ flag,
                            const float* __restrict__ dinv, int* __restrict__ cursor,
                            int2* __restrict__ csr, int E) {
  int e = blockIdx.x * blockDim.x + threadIdx.x;
  if (e >= E) return;
  int s, d;
  if (*flag) {
    const long long* p = (const long long*)ei;
    s = (int)p[e];
    d = (int)p[(size_t)E + e];
  } else {
    const int* p = (const int*)ei;
    s = p[e];
    d = p[(size_t)E + e];
  }
  int pos = atomicAdd(&cursor[d], 1);
  float nm = dinv[s] * dinv[d];
  csr[pos] = int2{s, __float_as_int(nm)};
}

// ---------------------------------------------------------------------------
// Weight transpose + bf16 convert: W[K][128] f32 -> Wt[128][K+8] bf16.
// ---------------------------------------------------------------------------
__global__ void convert_w_kernel(const float* __restrict__ W, ushort* __restrict__ Wt,
                                 int K, int KP) {
  int id = blockIdx.x * blockDim.x + threadIdx.x;
  if (id >= K * 128) return;
  int c = id & 127;
  int k = id >> 7;
  Wt[(size_t)c * KP + k] = f2bf(W[id]);
}

// W2[128][40] f32 -> W2t[48][128] bf16 (cols 40..47 zero-padded)
__global__ void convert_w2_kernel(const float* __restrict__ W2, ushort* __restrict__ Wt) {
  int id = blockIdx.x * blockDim.x + threadIdx.x;
  if (id >= 48 * 128) return;
  int c = id >> 7;
  int k = id & 127;
  Wt[(size_t)c * 128 + k] = (c < 40) ? f2bf(W2[(size_t)k * 40 + c]) : (ushort)0;
}

// ---------------------------------------------------------------------------
// B-in-LDS MFMA GEMM: out[M,128](bf16) = A[M,K] @ W. Wt fully staged in LDS.
// AF32 (K=512): DEPTH-2 prefetch — process 64 k per loop body with named
// register buffers (no runtime-indexed arrays -> no scratch); next
// iteration's 4 loads issue before this iteration's 16 MFMAs, so in-flight
// distance ~ a full iteration (~2x the depth-1 coverage that left r10's
// gemm512 latency-bound at ~2TB/s effective).
// ---------------------------------------------------------------------------
template <int K, bool AF32, bool BIAS_RELU, int WAVES>
__global__ __launch_bounds__(WAVES * 64, (WAVES == 16) ? 4 : 16 / WAVES)
void gemm_lds_kernel(
    const void* __restrict__ Ap, const ushort* __restrict__ Wtp,
    const float* __restrict__ bias, ushort* __restrict__ outp,
    int M, int rowsPerBlock) {
  constexpr int KP = K + 8;
  extern __shared__ __align__(16) ushort lB[];  // 128*KP
  const int tid = threadIdx.x;

  const int rowStart = blockIdx.x * rowsPerBlock;
  if (rowStart >= M) return;
  const int rowEnd = min(M, rowStart + rowsPerBlock);

  constexpr int TOTC = 128 * KP / 8;
  const s16x8* Wt8 = (const s16x8*)Wtp;
  for (int i = tid; i < TOTC; i += WAVES * 64) ((s16x8*)lB)[i] = Wt8[i];
  __syncthreads();

  const int w = tid >> 6;
  const int l = tid & 63;
  const int l15 = l & 15;
  const int kg = l >> 4;

  const ushort* Ab = (const ushort*)Ap;
  const float* Af = (const float*)Ap;

  for (int base = rowStart + w * 16; base < rowEnd; base += WAVES * 16) {
    int row = base + l15;
    if (row >= M) row = M - 1;  // clamp loads; stores guarded below

    f32x4 acc[8];
    #pragma unroll
    for (int c = 0; c < 8; ++c) acc[c] = f32x4{0.f, 0.f, 0.f, 0.f};

    if constexpr (AF32) {
      const float* ar = &Af[(size_t)row * K + kg * 8];
      f32x4 a0 = *(const f32x4*)(ar);
      f32x4 a1 = *(const f32x4*)(ar + 4);
      f32x4 b0 = *(const f32x4*)(ar + 32);
      f32x4 b1 = *(const f32x4*)(ar + 36);
      #pragma unroll
      for (int k0 = 0; k0 < K; k0 += 64) {
        f32x4 c0 = a0, c1 = a1, d0 = b0, d1 = b1;
        if (k0 + 64 < K) {  // issue next-iteration loads BEFORE the MFMAs
          a0 = *(const f32x4*)(ar + k0 + 64);
          a1 = *(const f32x4*)(ar + k0 + 68);
          b0 = *(const f32x4*)(ar + k0 + 96);
          b1 = *(const f32x4*)(ar + k0 + 100);
        }
        uint4 u;
        u.x = pk2bf(c0.x, c0.y); u.y = pk2bf(c0.z, c0.w);
        u.z = pk2bf(c1.x, c1.y); u.w = pk2bf(c1.z, c1.w);
        s16x8 af0 = *reinterpret_cast<s16x8*>(&u);
        #pragma unroll
        for (int c = 0; c < 8; ++c) {
          s16x8 bfr = *(const s16x8*)&lB[(16 * c + l15) * KP + k0 + kg * 8];
          acc[c] = __builtin_amdgcn_mfma_f32_16x16x32_bf16(af0, bfr, acc[c], 0, 0, 0);
        }
        uint4 u2;
        u2.x = pk2bf(d0.x, d0.y); u2.y = pk2bf(d0.z, d0.w);
        u2.z = pk2bf(d1.x, d1.y); u2.w = pk2bf(d1.z, d1.w);
        s16x8 af1 = *reinterpret_cast<s16x8*>(&u2);
        #pragma unroll
        for (int c = 0; c < 8; ++c) {
          s16x8 bfr = *(const s16x8*)&lB[(16 * c + l15) * KP + k0 + 32 + kg * 8];
          acc[c] = __builtin_amdgcn_mfma_f32_16x16x32_bf16(af1, bfr, acc[c], 0, 0, 0);
        }
      }
    } else {
      // K=128: preload all A fragments, then pure MFMA+LDS
      s16x8 afs[K / 32];
      #pragma unroll
      for (int k0 = 0; k0 < K; k0 += 32)
        afs[k0 / 32] = *(const s16x8*)&Ab[(size_t)row * K + k0 + kg * 8];
      #pragma unroll
      for (int k0 = 0; k0 < K; k0 += 32) {
        #pragma unroll
        for (int c = 0; c < 8; ++c) {
          s16x8 bfr = *(const s16x8*)&lB[(16 * c + l15) * KP + k0 + kg * 8];
          acc[c] = __builtin_amdgcn_mfma_f32_16x16x32_bf16(afs[k0 / 32], bfr, acc[c], 0, 0, 0);
        }
      }
    }

    #pragma unroll
    for (int c = 0; c < 8; ++c) {
      float b = 0.f;
      if constexpr (BIAS_RELU) b = bias[16 * c + l15];
      #pragma unroll
      for (int v = 0; v < 4; ++v) {
        int r = base + kg * 4 + v;
        if (r < M) {
          float val = acc[c][v];
          if constexpr (BIAS_RELU) val = fmaxf(val + b, 0.f);
          outp[(size_t)r * 128 + 16 * c + l15] = f2bf(val);
        }
      }
    }
  }
}

// ---------------------------------------------------------------------------
// Aggregation over bf16 hw: one wave per node; lane l covers cols 2l,2l+1.
// Packed int2 CSR, unrolled x8 (8 independent 256B gathers in flight).
// At ~5.7 TB/s effective gather bandwidth this is near the fabric ceiling.
// ---------------------------------------------------------------------------
__global__ __launch_bounds__(256) void aggregate_bf16_kernel(const ushort* __restrict__ hw,
    const int* __restrict__ off, const int2* __restrict__ csr,
    const float* __restrict__ dinv, const float* __restrict__ bias,
    ushort* __restrict__ out, int N) {
  int wid = (blockIdx.x * blockDim.x + threadIdx.x) >> 6;
  int lane = threadIdx.x & 63;
  if (wid >= N) return;
  const uint* hw4 = (const uint*)hw;
  int beg = off[wid], end = off[wid + 1];
  float ax = 0.f, ay = 0.f;
  int j = beg;
  int n8 = beg + ((end - beg) & ~7);
  for (; j < n8; j += 8) {
    int2 c0 = csr[j];     int2 c1 = csr[j + 1];
    int2 c2 = csr[j + 2]; int2 c3 = csr[j + 3];
    int2 c4 = csr[j + 4]; int2 c5 = csr[j + 5];
    int2 c6 = csr[j + 6]; int2 c7 = csr[j + 7];
    uint v0 = hw4[(size_t)c0.x * 64 + lane];
    uint v1 = hw4[(size_t)c1.x * 64 + lane];
    uint v2 = hw4[(size_t)c2.x * 64 + lane];
    uint v3 = hw4[(size_t)c3.x * 64 + lane];
    uint v4 = hw4[(size_t)c4.x * 64 + lane];
    uint v5 = hw4[(size_t)c5.x * 64 + lane];
    uint v6 = hw4[(size_t)c6.x * 64 + lane];
    uint v7 = hw4[(size_t)c7.x * 64 + lane];
    float n0 = __int_as_float(c0.y), n1 = __int_as_float(c1.y);
    float n2 = __int_as_float(c2.y), n3 = __int_as_float(c3.y);
    float n4 = __int_as_float(c4.y), n5 = __int_as_float(c5.y);
    float n6 = __int_as_float(c6.y), n7 = __int_as_float(c7.y);
    ax = fmaf(n0, bf2f_lo(v0), ax); ay = fmaf(n0, bf2f_hi(v0), ay);
    ax = fmaf(n1, bf2f_lo(v1), ax); ay = fmaf(n1, bf2f_hi(v1), ay);
    ax = fmaf(n2, bf2f_lo(v2), ax); ay = fmaf(n2, bf2f_hi(v2), ay);
    ax = fmaf(n3, bf2f_lo(v3), ax); ay = fmaf(n3, bf2f_hi(v3), ay);
    ax = fmaf(n4, bf2f_lo(v4), ax); ay = fmaf(n4, bf2f_hi(v4), ay);
    ax = fmaf(n5, bf2f_lo(v5), ax); ay = fmaf(n5, bf2f_hi(v5), ay);
    ax = fmaf(n6, bf2f_lo(v6), ax); ay = fmaf(n6, bf2f_hi(v6), ay);
    ax = fmaf(n7, bf2f_lo(v7), ax); ay = fmaf(n7, bf2f_hi(v7), ay);
  }
  if (j + 4 <= end) {
    int2 c0 = csr[j];     int2 c1 = csr[j + 1];
    int2 c2 = csr[j + 2]; int2 c3 = csr[j + 3];
    uint v0 = hw4[(size_t)c0.x * 64 + lane];
    uint v1 = hw4[(size_t)c1.x * 64 + lane];
    uint v2 = hw4[(size_t)c2.x * 64 + lane];
    uint v3 = hw4[(size_t)c3.x * 64 + lane];
    float n0 = __int_as_float(c0.y), n1 = __int_as_float(c1.y);
    float n2 = __int_as_float(c2.y), n3 = __int_as_float(c3.y);
    ax = fmaf(n0, bf2f_lo(v0), ax); ay = fmaf(n0, bf2f_hi(v0), ay);
    ax = fmaf(n1, bf2f_lo(v1), ax); ay = fmaf(n1, bf2f_hi(v1), ay);
    ax = fmaf(n2, bf2f_lo(v2), ax); ay = fmaf(n2, bf2f_hi(v2), ay);
    ax = fmaf(n3, bf2f_lo(v3), ax); ay = fmaf(n3, bf2f_hi(v3), ay);
    j += 4;
  }
  for (; j < end; ++j) {
    int2 c = csr[j];
    float nm = __int_as_float(c.y);
    uint v = hw4[(size_t)c.x * 64 + lane];
    ax = fmaf(nm, bf2f_lo(v), ax);
    ay = fmaf(nm, bf2f_hi(v), ay);
  }
  float di = dinv[wid];
  float snm = di * di;
  uint v = hw4[(size_t)wid * 64 + lane];
  ax = fmaf(snm, bf2f_lo(v), ax);
  ay = fmaf(snm, bf2f_hi(v), ay);
  float2 b = ((const float2*)bias)[lane];
  float ox = fmaxf(ax + b.x, 0.f);
  float oy = fmaxf(ay + b.y, 0.f);
  ((uint*)out)[(size_t)wid * 64 + lane] = pk2bf(ox, oy);
}

// ---------------------------------------------------------------------------
// Final: logits = h @ W2 + b2 (MFMA, 48-col padded) ; log_softmax epilogue.
// ---------------------------------------------------------------------------
__global__ __launch_bounds__(256) void final_mfma_kernel(const ushort* __restrict__ h,
    const ushort* __restrict__ W2t, const float* __restrict__ b2,
    float* __restrict__ out, int M) {
  const int tid = threadIdx.x;
  const int w = tid >> 6;
  const int l = tid & 63;
  const int l15 = l & 15;
  const int kg = l >> 4;
  const int base = (blockIdx.x * 4 + w) * 16;
  if (base >= M) return;
  int row = base + l15;
  if (row >= M) row = M - 1;

  f32x4 acc[3];
  #pragma unroll
  for (int c = 0; c < 3; ++c) acc[c] = f32x4{0.f, 0.f, 0.f, 0.f};

  #pragma unroll
  for (int k0 = 0; k0 < 128; k0 += 32) {
    s16x8 af = *(const s16x8*)&h[(size_t)row * 128 + k0 + kg * 8];
    #pragma unroll
    for (int c = 0; c < 3; ++c) {
      s16x8 bfr = *(const s16x8*)&W2t[(size_t)(16 * c + l15) * 128 + k0 + kg * 8];
      acc[c] = __builtin_amdgcn_mfma_f32_16x16x32_bf16(af, bfr, acc[c], 0, 0, 0);
    }
  }

  float bv0 = b2[l15];
  float bv1 = b2[16 + l15];
  float bv2 = (l15 < 8) ? b2[32 + l15] : 0.f;

  #pragma unroll
  for (int v = 0; v < 4; ++v) {
    float l0 = acc[0][v] + bv0;
    float l1 = acc[1][v] + bv1;
    float l2 = (l15 < 8) ? (acc[2][v] + bv2) : -1e30f;
    float pm = fmaxf(fmaxf(l0, l1), l2);
    #pragma unroll
    for (int sh = 8; sh > 0; sh >>= 1) pm = fmaxf(pm, __shfl_xor(pm, sh));
    float es = expf(l0 - pm) + expf(l1 - pm) + ((l15 < 8) ? expf(l2 - pm) : 0.f);
    #pragma unroll
    for (int sh = 8; sh > 0; sh >>= 1) es += __shfl_xor(es, sh);
    float lse = pm + logf(es);
    int r = base + kg * 4 + v;
    if (r < M) {
      out[(size_t)r * 40 + l15] = l0 - lse;
      out[(size_t)r * 40 + 16 + l15] = l1 - lse;
      if (l15 < 8) out[(size_t)r * 40 + 32 + l15] = l2 - lse;
    }
  }
}

// ---------------------------------------------------------------------------
extern "C" void kernel_launch(void* const* d_in, const int* in_sizes, int n_in,
                              void* d_out, int out_size, void* d_ws, size_t ws_size,
                              hipStream_t stream) {
  const float* x   = (const float*)d_in[0];
  const void*  ei  = d_in[1];
  const float* W1  = (const float*)d_in[2];
  const float* b1  = (const float*)d_in[3];
  const float* Wg0 = (const float*)d_in[4];
  const float* bg0 = (const float*)d_in[5];
  const float* Wg1 = (const float*)d_in[6];
  const float* bg1 = (const float*)d_in[7];
  const float* W2  = (const float*)d_in[8];
  const float* b2  = (const float*)d_in[9];
  float* out = (float*)d_out;

  const int N = in_sizes[0] / 512;
  const int E = in_sizes[1] / 2;

  char* wsb = (char*)d_ws;
  size_t o = 0;
  auto alloc = [&](size_t bytes) -> void* {
    void* p = wsb + o;
    o = align_up(o + bytes, 256);
    return p;
  };
  int*    flag    = (int*)alloc(4);
  int*    cnt     = (int*)alloc((size_t)N * 4);
  float*  dinv    = (float*)alloc((size_t)N * 4);
  int*    off     = (int*)alloc((size_t)(N + 1) * 4);
  int*    cursor  = (int*)alloc((size_t)N * 4);
  int*    bsum    = (int*)alloc(128 * 4);
  int*    boff    = (int*)alloc(128 * 4);
  int2*   csr     = (int2*)alloc((size_t)E * 8);
  ushort* W1t     = (ushort*)alloc((size_t)128 * 520 * 2);
  ushort* Wg0t    = (ushort*)alloc((size_t)128 * 136 * 2);
  ushort* Wg1t    = (ushort*)alloc((size_t)128 * 136 * 2);
  ushort* W2t     = (ushort*)alloc((size_t)48 * 128 * 2);
  ushort* hb1     = (ushort*)alloc((size_t)N * HID * 2);
  ushort* hb2     = (ushort*)alloc((size_t)N * HID * 2);
  (void)ws_size; (void)n_in; (void)out_size;

  const int tpb = 256;
  const int ebl = (E + tpb - 1) / tpb;
  const int nbl = (N + tpb - 1) / tpb;

  // --- graph prep ---
  detect_i64_kernel<<<1, 256, 0, stream>>>((const unsigned int*)ei, 2 * E, flag);
  hipMemsetAsync(cnt, 0, (size_t)N * 4, stream);
  count_kernel<<<ebl, tpb, 0, stream>>>(ei, flag, E, cnt);
  const int nsb = (N + 1023) / 1024;
  scan_local_kernel<<<nsb, 1024, 0, stream>>>(cnt, off, bsum, dinv, N);
  scan_bsum_kernel<<<1, 128, 0, stream>>>(bsum, nsb, boff, off + N);
  scan_add_kernel<<<nbl, tpb, 0, stream>>>(off, boff, cursor, N);
  fill_kernel<<<ebl, tpb, 0, stream>>>(ei, flag, dinv, cursor, csr, E);

  // --- weight prep ---
  convert_w_kernel<<<(512 * 128 + 255) / 256, 256, 0, stream>>>(W1, W1t, 512, 520);
  convert_w_kernel<<<(128 * 128 + 255) / 256, 256, 0, stream>>>(Wg0, Wg0t, 128, 136);
  convert_w_kernel<<<(128 * 128 + 255) / 256, 256, 0, stream>>>(Wg1, Wg1t, 128, 136);
  convert_w2_kernel<<<(48 * 128 + 255) / 256, 256, 0, stream>>>(W2, W2t);

  // --- network ---
  const size_t lds512 = (size_t)128 * 520 * 2;
  const size_t lds128 = (size_t)128 * 136 * 2;
  static bool attr_done = false;
  if (!attr_done) {
    (void)hipFuncSetAttribute(
        reinterpret_cast<const void*>(&gemm_lds_kernel<512, true, true, 16>),
        hipFuncAttributeMaxDynamicSharedMemorySize, (int)lds512);
    attr_done = true;
  }

  int rpb512 = (N + 255) / 256;
  rpb512 = (rpb512 + 15) & ~15;
  const int grid512 = (N + rpb512 - 1) / rpb512;
  const int rpb128 = 128;
  const int grid128 = (N + rpb128 - 1) / rpb128;
  const int abl = (N * 64 + tpb - 1) / tpb;
  const int fbl = (N + 63) / 64;

  gemm_lds_kernel<512, true, true, 16><<<grid512, 1024, lds512, stream>>>(
      x, W1t, b1, hb1, N, rpb512);

  gemm_lds_kernel<128, false, false, 4><<<grid128, 256, lds128, stream>>>(
      hb1, Wg0t, nullptr, hb2, N, rpb128);
  aggregate_bf16_kernel<<<abl, tpb, 0, stream>>>(hb2, off, csr, dinv, bg0, hb1, N);

  gemm_lds_kernel<128, false, false, 4><<<grid128, 256, lds128, stream>>>(
      hb1, Wg1t, nullptr, hb2, N, rpb128);
  aggregate_bf16_kernel<<<abl, tpb, 0, stream>>>(hb2, off, csr, dinv, bg1, hb1, N);

  final_mfma_kernel<<<fbl, 256, 0, stream>>>(hb1, W2t, b2, out, N);
}

// Round 12
// 458.934 us; speedup vs baseline: 1.6436x; 1.6436x over previous
//
#include <hip/hip_runtime.h>
#include <hip/hip_bf16.h>
#include <cstdint>

#define HID 128

typedef short s16x8 __attribute__((ext_vector_type(8)));
typedef float f32x4 __attribute__((ext_vector_type(4)));

static inline size_t align_up(size_t x, size_t a) { return (x + a - 1) & ~(a - 1); }

__device__ inline ushort f2bf(float f) {  // RNE bit-hack (cold paths)
  uint u = __float_as_uint(f);
  u += 0x7FFFu + ((u >> 16) & 1u);
  return (ushort)(u >> 16);
}
// Hot-path pair convert -> v_cvt_pk_bf16_f32 (RNE, same result)
__device__ inline uint pk2bf(float lo, float hi) {
  __hip_bfloat162 h = __float22bfloat162_rn(float2{lo, hi});
  return *reinterpret_cast<uint*>(&h);
}
__device__ inline float bf2f_lo(uint v) { return __uint_as_float(v << 16); }
__device__ inline float bf2f_hi(uint v) { return __uint_as_float(v & 0xFFFF0000u); }

// ---------------------------------------------------------------------------
// Edge dtype sniffer.
// ---------------------------------------------------------------------------
__global__ void detect_i64_kernel(const unsigned int* __restrict__ p, int nwords,
                                  int* __restrict__ flag) {
  __shared__ int any;
  if (threadIdx.x == 0) any = 0;
  __syncthreads();
  for (int i = threadIdx.x; i < 1024; i += blockDim.x) {
    int w = 2 * i + 1;
    if (w < nwords && p[w] != 0u) atomicOr(&any, 1);
  }
  __syncthreads();
  if (threadIdx.x == 0) *flag = (any == 0) ? 1 : 0;
}

// degree count: reads only the dst half of edge_index
__global__ void count_kernel(const void* __restrict__ ei, const int* __restrict__ flag,
                             int E, int* __restrict__ cnt) {
  int e = blockIdx.x * blockDim.x + threadIdx.x;
  if (e >= E) return;
  int d;
  if (*flag) d = (int)((const long long*)ei)[(size_t)E + e];
  else       d = ((const int*)ei)[(size_t)E + e];
  atomicAdd(&cnt[d], 1);
}

// ---------------------------------------------------------------------------
// Two-level exclusive scan over per-node counts -> CSR row offsets.
// dinv folded in.
// ---------------------------------------------------------------------------
__global__ __launch_bounds__(1024) void scan_local_kernel(const int* __restrict__ cnt,
    int* __restrict__ off, int* __restrict__ bsum, float* __restrict__ dinv, int N) {
  __shared__ int buf[1024];
  int tid = threadIdx.x;
  int i = blockIdx.x * 1024 + tid;
  int v = (i < N) ? cnt[i] : 0;
  buf[tid] = v;
  __syncthreads();
  #pragma unroll
  for (int s = 1; s < 1024; s <<= 1) {
    int t = (tid >= s) ? buf[tid - s] : 0;
    __syncthreads();
    buf[tid] += t;
    __syncthreads();
  }
  if (i < N) {
    off[i] = buf[tid] - v;
    dinv[i] = rsqrtf((float)(v + 1));  // +1 self-loop
  }
  if (tid == 1023) bsum[blockIdx.x] = buf[1023];
}

__global__ __launch_bounds__(128) void scan_bsum_kernel(const int* __restrict__ bsum, int nb,
    int* __restrict__ boff, int* __restrict__ offN) {
  __shared__ int b[128];
  int tid = threadIdx.x;
  int v = (tid < nb) ? bsum[tid] : 0;
  b[tid] = v;
  __syncthreads();
  #pragma unroll
  for (int s = 1; s < 128; s <<= 1) {
    int t = (tid >= s) ? b[tid - s] : 0;
    __syncthreads();
    b[tid] += t;
    __syncthreads();
  }
  if (tid < nb) boff[tid] = b[tid] - v;
  if (tid == 127) *offN = b[127];
}

__global__ void scan_add_kernel(int* __restrict__ off, const int* __restrict__ boff,
                                int* __restrict__ cursor, int N) {
  int i = blockIdx.x * blockDim.x + threadIdx.x;
  if (i >= N) return;
  int o = off[i] + boff[i >> 10];
  off[i] = o;
  cursor[i] = o;
}

// CSR fill: re-reads edge_index directly (L3-hot); one packed 8B scatter/edge.
__global__ void fill_kernel(const void* __restrict__ ei, const int* __restrict__ flag,
                            const float* __restrict__ dinv, int* __restrict__ cursor,
                            int2* __restrict__ csr, int E) {
  int e = blockIdx.x * blockDim.x + threadIdx.x;
  if (e >= E) return;
  int s, d;
  if (*flag) {
    const long long* p = (const long long*)ei;
    s = (int)p[e];
    d = (int)p[(size_t)E + e];
  } else {
    const int* p = (const int*)ei;
    s = p[e];
    d = p[(size_t)E + e];
  }
  int pos = atomicAdd(&cursor[d], 1);
  float nm = dinv[s] * dinv[d];
  csr[pos] = int2{s, __float_as_int(nm)};
}

// ---------------------------------------------------------------------------
// Weight transpose + bf16 convert: W[K][128] f32 -> Wt[128][K+8] bf16.
// ---------------------------------------------------------------------------
__global__ void convert_w_kernel(const float* __restrict__ W, ushort* __restrict__ Wt,
                                 int K, int KP) {
  int id = blockIdx.x * blockDim.x + threadIdx.x;
  if (id >= K * 128) return;
  int c = id & 127;
  int k = id >> 7;
  Wt[(size_t)c * KP + k] = f2bf(W[id]);
}

// W2[128][40] f32 -> W2t[48][128] bf16 (cols 40..47 zero-padded)
__global__ void convert_w2_kernel(const float* __restrict__ W2, ushort* __restrict__ Wt) {
  int id = blockIdx.x * blockDim.x + threadIdx.x;
  if (id >= 48 * 128) return;
  int c = id >> 7;
  int k = id & 127;
  Wt[(size_t)c * 128 + k] = (c < 40) ? f2bf(W2[(size_t)k * 40 + c]) : (ushort)0;
}

// ---------------------------------------------------------------------------
// B-in-LDS MFMA GEMM: out[M,128](bf16) = A[M,K] @ W. Wt fully staged in LDS.
// AF32 (K=512): depth-1 named-register prefetch, ROLLED x4 unroll (r9-proven).
// r11 lesson: full-unroll + deeper prefetch hoists all iterations' loads ->
// register explosion -> 900MB scratch spill traffic. Keep the loop rolled.
// ---------------------------------------------------------------------------
template <int K, bool AF32, bool BIAS_RELU, int WAVES>
__global__ __launch_bounds__(WAVES * 64, (WAVES == 16) ? 4 : 16 / WAVES)
void gemm_lds_kernel(
    const void* __restrict__ Ap, const ushort* __restrict__ Wtp,
    const float* __restrict__ bias, ushort* __restrict__ outp,
    int M, int rowsPerBlock) {
  constexpr int KP = K + 8;
  extern __shared__ __align__(16) ushort lB[];  // 128*KP
  const int tid = threadIdx.x;

  const int rowStart = blockIdx.x * rowsPerBlock;
  if (rowStart >= M) return;
  const int rowEnd = min(M, rowStart + rowsPerBlock);

  constexpr int TOTC = 128 * KP / 8;
  const s16x8* Wt8 = (const s16x8*)Wtp;
  for (int i = tid; i < TOTC; i += WAVES * 64) ((s16x8*)lB)[i] = Wt8[i];
  __syncthreads();

  const int w = tid >> 6;
  const int l = tid & 63;
  const int l15 = l & 15;
  const int kg = l >> 4;

  const ushort* Ab = (const ushort*)Ap;
  const float* Af = (const float*)Ap;

  for (int base = rowStart + w * 16; base < rowEnd; base += WAVES * 16) {
    int row = base + l15;
    if (row >= M) row = M - 1;  // clamp loads; stores guarded below

    f32x4 acc[8];
    #pragma unroll
    for (int c = 0; c < 8; ++c) acc[c] = f32x4{0.f, 0.f, 0.f, 0.f};

    if constexpr (AF32) {
      const float* ar = &Af[(size_t)row * K + kg * 8];
      f32x4 p0 = *(const f32x4*)ar;
      f32x4 p1 = *(const f32x4*)(ar + 4);
      #pragma unroll 4
      for (int k0 = 0; k0 < K; k0 += 32) {
        f32x4 c0 = p0, c1 = p1;
        if (k0 + 32 < K) {           // issue next-step loads BEFORE MFMAs
          p0 = *(const f32x4*)(ar + k0 + 32);
          p1 = *(const f32x4*)(ar + k0 + 36);
        }
        uint4 u;
        u.x = pk2bf(c0.x, c0.y);
        u.y = pk2bf(c0.z, c0.w);
        u.z = pk2bf(c1.x, c1.y);
        u.w = pk2bf(c1.z, c1.w);
        s16x8 af = *reinterpret_cast<s16x8*>(&u);
        #pragma unroll
        for (int c = 0; c < 8; ++c) {
          s16x8 bfr = *(const s16x8*)&lB[(16 * c + l15) * KP + k0 + kg * 8];
          acc[c] = __builtin_amdgcn_mfma_f32_16x16x32_bf16(af, bfr, acc[c], 0, 0, 0);
        }
      }
    } else {
      // K=128: preload all A fragments, then pure MFMA+LDS
      s16x8 afs[K / 32];
      #pragma unroll
      for (int k0 = 0; k0 < K; k0 += 32)
        afs[k0 / 32] = *(const s16x8*)&Ab[(size_t)row * K + k0 + kg * 8];
      #pragma unroll
      for (int k0 = 0; k0 < K; k0 += 32) {
        #pragma unroll
        for (int c = 0; c < 8; ++c) {
          s16x8 bfr = *(const s16x8*)&lB[(16 * c + l15) * KP + k0 + kg * 8];
          acc[c] = __builtin_amdgcn_mfma_f32_16x16x32_bf16(afs[k0 / 32], bfr, acc[c], 0, 0, 0);
        }
      }
    }

    #pragma unroll
    for (int c = 0; c < 8; ++c) {
      float b = 0.f;
      if constexpr (BIAS_RELU) b = bias[16 * c + l15];
      #pragma unroll
      for (int v = 0; v < 4; ++v) {
        int r = base + kg * 4 + v;
        if (r < M) {
          float val = acc[c][v];
          if constexpr (BIAS_RELU) val = fmaxf(val + b, 0.f);
          outp[(size_t)r * 128 + 16 * c + l15] = f2bf(val);
        }
      }
    }
  }
}

// ---------------------------------------------------------------------------
// Aggregation over bf16 hw: one wave per node; lane l covers cols 2l,2l+1.
// Packed int2 CSR, unrolled x8 (8 independent 256B gathers in flight).
// At ~5.7 TB/s effective gather bandwidth this is near the fabric ceiling.
// ---------------------------------------------------------------------------
__global__ __launch_bounds__(256) void aggregate_bf16_kernel(const ushort* __restrict__ hw,
    const int* __restrict__ off, const int2* __restrict__ csr,
    const float* __restrict__ dinv, const float* __restrict__ bias,
    ushort* __restrict__ out, int N) {
  int wid = (blockIdx.x * blockDim.x + threadIdx.x) >> 6;
  int lane = threadIdx.x & 63;
  if (wid >= N) return;
  const uint* hw4 = (const uint*)hw;
  int beg = off[wid], end = off[wid + 1];
  float ax = 0.f, ay = 0.f;
  int j = beg;
  int n8 = beg + ((end - beg) & ~7);
  for (; j < n8; j += 8) {
    int2 c0 = csr[j];     int2 c1 = csr[j + 1];
    int2 c2 = csr[j + 2]; int2 c3 = csr[j + 3];
    int2 c4 = csr[j + 4]; int2 c5 = csr[j + 5];
    int2 c6 = csr[j + 6]; int2 c7 = csr[j + 7];
    uint v0 = hw4[(size_t)c0.x * 64 + lane];
    uint v1 = hw4[(size_t)c1.x * 64 + lane];
    uint v2 = hw4[(size_t)c2.x * 64 + lane];
    uint v3 = hw4[(size_t)c3.x * 64 + lane];
    uint v4 = hw4[(size_t)c4.x * 64 + lane];
    uint v5 = hw4[(size_t)c5.x * 64 + lane];
    uint v6 = hw4[(size_t)c6.x * 64 + lane];
    uint v7 = hw4[(size_t)c7.x * 64 + lane];
    float n0 = __int_as_float(c0.y), n1 = __int_as_float(c1.y);
    float n2 = __int_as_float(c2.y), n3 = __int_as_float(c3.y);
    float n4 = __int_as_float(c4.y), n5 = __int_as_float(c5.y);
    float n6 = __int_as_float(c6.y), n7 = __int_as_float(c7.y);
    ax = fmaf(n0, bf2f_lo(v0), ax); ay = fmaf(n0, bf2f_hi(v0), ay);
    ax = fmaf(n1, bf2f_lo(v1), ax); ay = fmaf(n1, bf2f_hi(v1), ay);
    ax = fmaf(n2, bf2f_lo(v2), ax); ay = fmaf(n2, bf2f_hi(v2), ay);
    ax = fmaf(n3, bf2f_lo(v3), ax); ay = fmaf(n3, bf2f_hi(v3), ay);
    ax = fmaf(n4, bf2f_lo(v4), ax); ay = fmaf(n4, bf2f_hi(v4), ay);
    ax = fmaf(n5, bf2f_lo(v5), ax); ay = fmaf(n5, bf2f_hi(v5), ay);
    ax = fmaf(n6, bf2f_lo(v6), ax); ay = fmaf(n6, bf2f_hi(v6), ay);
    ax = fmaf(n7, bf2f_lo(v7), ax); ay = fmaf(n7, bf2f_hi(v7), ay);
  }
  if (j + 4 <= end) {
    int2 c0 = csr[j];     int2 c1 = csr[j + 1];
    int2 c2 = csr[j + 2]; int2 c3 = csr[j + 3];
    uint v0 = hw4[(size_t)c0.x * 64 + lane];
    uint v1 = hw4[(size_t)c1.x * 64 + lane];
    uint v2 = hw4[(size_t)c2.x * 64 + lane];
    uint v3 = hw4[(size_t)c3.x * 64 + lane];
    float n0 = __int_as_float(c0.y), n1 = __int_as_float(c1.y);
    float n2 = __int_as_float(c2.y), n3 = __int_as_float(c3.y);
    ax = fmaf(n0, bf2f_lo(v0), ax); ay = fmaf(n0, bf2f_hi(v0), ay);
    ax = fmaf(n1, bf2f_lo(v1), ax); ay = fmaf(n1, bf2f_hi(v1), ay);
    ax = fmaf(n2, bf2f_lo(v2), ax); ay = fmaf(n2, bf2f_hi(v2), ay);
    ax = fmaf(n3, bf2f_lo(v3), ax); ay = fmaf(n3, bf2f_hi(v3), ay);
    j += 4;
  }
  for (; j < end; ++j) {
    int2 c = csr[j];
    float nm = __int_as_float(c.y);
    uint v = hw4[(size_t)c.x * 64 + lane];
    ax = fmaf(nm, bf2f_lo(v), ax);
    ay = fmaf(nm, bf2f_hi(v), ay);
  }
  float di = dinv[wid];
  float snm = di * di;
  uint v = hw4[(size_t)wid * 64 + lane];
  ax = fmaf(snm, bf2f_lo(v), ax);
  ay = fmaf(snm, bf2f_hi(v), ay);
  float2 b = ((const float2*)bias)[lane];
  float ox = fmaxf(ax + b.x, 0.f);
  float oy = fmaxf(ay + b.y, 0.f);
  ((uint*)out)[(size_t)wid * 64 + lane] = pk2bf(ox, oy);
}

// ---------------------------------------------------------------------------
// Final: logits = h @ W2 + b2 (MFMA, 48-col padded) ; log_softmax epilogue.
// ---------------------------------------------------------------------------
__global__ __launch_bounds__(256) void final_mfma_kernel(const ushort* __restrict__ h,
    const ushort* __restrict__ W2t, const float* __restrict__ b2,
    float* __restrict__ out, int M) {
  const int tid = threadIdx.x;
  const int w = tid >> 6;
  const int l = tid & 63;
  const int l15 = l & 15;
  const int kg = l >> 4;
  const int base = (blockIdx.x * 4 + w) * 16;
  if (base >= M) return;
  int row = base + l15;
  if (row >= M) row = M - 1;

  f32x4 acc[3];
  #pragma unroll
  for (int c = 0; c < 3; ++c) acc[c] = f32x4{0.f, 0.f, 0.f, 0.f};

  #pragma unroll
  for (int k0 = 0; k0 < 128; k0 += 32) {
    s16x8 af = *(const s16x8*)&h[(size_t)row * 128 + k0 + kg * 8];
    #pragma unroll
    for (int c = 0; c < 3; ++c) {
      s16x8 bfr = *(const s16x8*)&W2t[(size_t)(16 * c + l15) * 128 + k0 + kg * 8];
      acc[c] = __builtin_amdgcn_mfma_f32_16x16x32_bf16(af, bfr, acc[c], 0, 0, 0);
    }
  }

  float bv0 = b2[l15];
  float bv1 = b2[16 + l15];
  float bv2 = (l15 < 8) ? b2[32 + l15] : 0.f;

  #pragma unroll
  for (int v = 0; v < 4; ++v) {
    float l0 = acc[0][v] + bv0;
    float l1 = acc[1][v] + bv1;
    float l2 = (l15 < 8) ? (acc[2][v] + bv2) : -1e30f;
    float pm = fmaxf(fmaxf(l0, l1), l2);
    #pragma unroll
    for (int sh = 8; sh > 0; sh >>= 1) pm = fmaxf(pm, __shfl_xor(pm, sh));
    float es = expf(l0 - pm) + expf(l1 - pm) + ((l15 < 8) ? expf(l2 - pm) : 0.f);
    #pragma unroll
    for (int sh = 8; sh > 0; sh >>= 1) es += __shfl_xor(es, sh);
    float lse = pm + logf(es);
    int r = base + kg * 4 + v;
    if (r < M) {
      out[(size_t)r * 40 + l15] = l0 - lse;
      out[(size_t)r * 40 + 16 + l15] = l1 - lse;
      if (l15 < 8) out[(size_t)r * 40 + 32 + l15] = l2 - lse;
    }
  }
}

// ---------------------------------------------------------------------------
extern "C" void kernel_launch(void* const* d_in, const int* in_sizes, int n_in,
                              void* d_out, int out_size, void* d_ws, size_t ws_size,
                              hipStream_t stream) {
  const float* x   = (const float*)d_in[0];
  const void*  ei  = d_in[1];
  const float* W1  = (const float*)d_in[2];
  const float* b1  = (const float*)d_in[3];
  const float* Wg0 = (const float*)d_in[4];
  const float* bg0 = (const float*)d_in[5];
  const float* Wg1 = (const float*)d_in[6];
  const float* bg1 = (const float*)d_in[7];
  const float* W2  = (const float*)d_in[8];
  const float* b2  = (const float*)d_in[9];
  float* out = (float*)d_out;

  const int N = in_sizes[0] / 512;
  const int E = in_sizes[1] / 2;

  char* wsb = (char*)d_ws;
  size_t o = 0;
  auto alloc = [&](size_t bytes) -> void* {
    void* p = wsb + o;
    o = align_up(o + bytes, 256);
    return p;
  };
  int*    flag    = (int*)alloc(4);
  int*    cnt     = (int*)alloc((size_t)N * 4);
  float*  dinv    = (float*)alloc((size_t)N * 4);
  int*    off     = (int*)alloc((size_t)(N + 1) * 4);
  int*    cursor  = (int*)alloc((size_t)N * 4);
  int*    bsum    = (int*)alloc(128 * 4);
  int*    boff    = (int*)alloc(128 * 4);
  int2*   csr     = (int2*)alloc((size_t)E * 8);
  ushort* W1t     = (ushort*)alloc((size_t)128 * 520 * 2);
  ushort* Wg0t    = (ushort*)alloc((size_t)128 * 136 * 2);
  ushort* Wg1t    = (ushort*)alloc((size_t)128 * 136 * 2);
  ushort* W2t     = (ushort*)alloc((size_t)48 * 128 * 2);
  ushort* hb1     = (ushort*)alloc((size_t)N * HID * 2);
  ushort* hb2     = (ushort*)alloc((size_t)N * HID * 2);
  (void)ws_size; (void)n_in; (void)out_size;

  const int tpb = 256;
  const int ebl = (E + tpb - 1) / tpb;
  const int nbl = (N + tpb - 1) / tpb;

  // --- graph prep ---
  detect_i64_kernel<<<1, 256, 0, stream>>>((const unsigned int*)ei, 2 * E, flag);
  hipMemsetAsync(cnt, 0, (size_t)N * 4, stream);
  count_kernel<<<ebl, tpb, 0, stream>>>(ei, flag, E, cnt);
  const int nsb = (N + 1023) / 1024;
  scan_local_kernel<<<nsb, 1024, 0, stream>>>(cnt, off, bsum, dinv, N);
  scan_bsum_kernel<<<1, 128, 0, stream>>>(bsum, nsb, boff, off + N);
  scan_add_kernel<<<nbl, tpb, 0, stream>>>(off, boff, cursor, N);
  fill_kernel<<<ebl, tpb, 0, stream>>>(ei, flag, dinv, cursor, csr, E);

  // --- weight prep ---
  convert_w_kernel<<<(512 * 128 + 255) / 256, 256, 0, stream>>>(W1, W1t, 512, 520);
  convert_w_kernel<<<(128 * 128 + 255) / 256, 256, 0, stream>>>(Wg0, Wg0t, 128, 136);
  convert_w_kernel<<<(128 * 128 + 255) / 256, 256, 0, stream>>>(Wg1, Wg1t, 128, 136);
  convert_w2_kernel<<<(48 * 128 + 255) / 256, 256, 0, stream>>>(W2, W2t);

  // --- network ---
  const size_t lds512 = (size_t)128 * 520 * 2;
  const size_t lds128 = (size_t)128 * 136 * 2;
  static bool attr_done = false;
  if (!attr_done) {
    (void)hipFuncSetAttribute(
        reinterpret_cast<const void*>(&gemm_lds_kernel<512, true, true, 16>),
        hipFuncAttributeMaxDynamicSharedMemorySize, (int)lds512);
    attr_done = true;
  }

  int rpb512 = (N + 255) / 256;
  rpb512 = (rpb512 + 15) & ~15;
  const int grid512 = (N + rpb512 - 1) / rpb512;
  const int rpb128 = 128;
  const int grid128 = (N + rpb128 - 1) / rpb128;
  const int abl = (N * 64 + tpb - 1) / tpb;
  const int fbl = (N + 63) / 64;

  gemm_lds_kernel<512, true, true, 16><<<grid512, 1024, lds512, stream>>>(
      x, W1t, b1, hb1, N, rpb512);

  gemm_lds_kernel<128, false, false, 4><<<grid128, 256, lds128, stream>>>(
      hb1, Wg0t, nullptr, hb2, N, rpb128);
  aggregate_bf16_kernel<<<abl, tpb, 0, stream>>>(hb2, off, csr, dinv, bg0, hb1, N);

  gemm_lds_kernel<128, false, false, 4><<<grid128, 256, lds128, stream>>>(
      hb1, Wg1t, nullptr, hb2, N, rpb128);
  aggregate_bf16_kernel<<<abl, tpb, 0, stream>>>(hb2, off, csr, dinv, bg1, hb1, N);

  final_mfma_kernel<<<fbl, 256, 0, stream>>>(hb1, W2t, b2, out, N);
}

// Round 13
// 454.519 us; speedup vs baseline: 1.6595x; 1.0097x over previous
//
#include <hip/hip_runtime.h>
#include <hip/hip_bf16.h>
#include <cstdint>

#define HID 128

typedef short s16x8 __attribute__((ext_vector_type(8)));
typedef float f32x4 __attribute__((ext_vector_type(4)));

static inline size_t align_up(size_t x, size_t a) { return (x + a - 1) & ~(a - 1); }

__device__ inline ushort f2bf(float f) {  // RNE bit-hack (cold paths)
  uint u = __float_as_uint(f);
  u += 0x7FFFu + ((u >> 16) & 1u);
  return (ushort)(u >> 16);
}
// Hot-path pair convert -> v_cvt_pk_bf16_f32 (RNE, same result)
__device__ inline uint pk2bf(float lo, float hi) {
  __hip_bfloat162 h = __float22bfloat162_rn(float2{lo, hi});
  return *reinterpret_cast<uint*>(&h);
}
__device__ inline float bf2f_lo(uint v) { return __uint_as_float(v << 16); }
__device__ inline float bf2f_hi(uint v) { return __uint_as_float(v & 0xFFFF0000u); }

// ---------------------------------------------------------------------------
// Fused: zero cnt[] + edge-dtype sniff (block 0). Replaces memsetAsync +
// detect dispatch. flag is consumed by LATER dispatches only (kernel-boundary
// visibility).
// ---------------------------------------------------------------------------
__global__ void zero_detect_kernel(int* __restrict__ cnt, int N,
                                   const unsigned int* __restrict__ p, int nwords,
                                   int* __restrict__ flag) {
  int i = blockIdx.x * blockDim.x + threadIdx.x;
  if (i < N) cnt[i] = 0;
  if (blockIdx.x == 0) {
    __shared__ int any;
    if (threadIdx.x == 0) any = 0;
    __syncthreads();
    for (int k = threadIdx.x; k < 1024; k += blockDim.x) {
      int w = 2 * k + 1;
      if (w < nwords && p[w] != 0u) atomicOr(&any, 1);
    }
    __syncthreads();
    if (threadIdx.x == 0) *flag = (any == 0) ? 1 : 0;
  }
}

// degree count: reads only the dst half of edge_index
__global__ void count_kernel(const void* __restrict__ ei, const int* __restrict__ flag,
                             int E, int* __restrict__ cnt) {
  int e = blockIdx.x * blockDim.x + threadIdx.x;
  if (e >= E) return;
  int d;
  if (*flag) d = (int)((const long long*)ei)[(size_t)E + e];
  else       d = ((const int*)ei)[(size_t)E + e];
  atomicAdd(&cnt[d], 1);
}

// ---------------------------------------------------------------------------
// Two-level exclusive scan over per-node counts -> CSR row offsets.
// dinv folded in.
// ---------------------------------------------------------------------------
__global__ __launch_bounds__(1024) void scan_local_kernel(const int* __restrict__ cnt,
    int* __restrict__ off, int* __restrict__ bsum, float* __restrict__ dinv, int N) {
  __shared__ int buf[1024];
  int tid = threadIdx.x;
  int i = blockIdx.x * 1024 + tid;
  int v = (i < N) ? cnt[i] : 0;
  buf[tid] = v;
  __syncthreads();
  #pragma unroll
  for (int s = 1; s < 1024; s <<= 1) {
    int t = (tid >= s) ? buf[tid - s] : 0;
    __syncthreads();
    buf[tid] += t;
    __syncthreads();
  }
  if (i < N) {
    off[i] = buf[tid] - v;
    dinv[i] = rsqrtf((float)(v + 1));  // +1 self-loop
  }
  if (tid == 1023) bsum[blockIdx.x] = buf[1023];
}

__global__ __launch_bounds__(128) void scan_bsum_kernel(const int* __restrict__ bsum, int nb,
    int* __restrict__ boff, int* __restrict__ offN) {
  __shared__ int b[128];
  int tid = threadIdx.x;
  int v = (tid < nb) ? bsum[tid] : 0;
  b[tid] = v;
  __syncthreads();
  #pragma unroll
  for (int s = 1; s < 128; s <<= 1) {
    int t = (tid >= s) ? b[tid - s] : 0;
    __syncthreads();
    b[tid] += t;
    __syncthreads();
  }
  if (tid < nb) boff[tid] = b[tid] - v;
  if (tid == 127) *offN = b[127];
}

__global__ void scan_add_kernel(int* __restrict__ off, const int* __restrict__ boff,
                                int* __restrict__ cursor, int N) {
  int i = blockIdx.x * blockDim.x + threadIdx.x;
  if (i >= N) return;
  int o = off[i] + boff[i >> 10];
  off[i] = o;
  cursor[i] = o;
}

// CSR fill: re-reads edge_index directly (L3-hot); one packed 8B scatter/edge.
__global__ void fill_kernel(const void* __restrict__ ei, const int* __restrict__ flag,
                            const float* __restrict__ dinv, int* __restrict__ cursor,
                            int2* __restrict__ csr, int E) {
  int e = blockIdx.x * blockDim.x + threadIdx.x;
  if (e >= E) return;
  int s, d;
  if (*flag) {
    const long long* p = (const long long*)ei;
    s = (int)p[e];
    d = (int)p[(size_t)E + e];
  } else {
    const int* p = (const int*)ei;
    s = p[e];
    d = p[(size_t)E + e];
  }
  int pos = atomicAdd(&cursor[d], 1);
  float nm = dinv[s] * dinv[d];
  csr[pos] = int2{s, __float_as_int(nm)};
}

// ---------------------------------------------------------------------------
// ALL weight conversions in one dispatch, id-range partitioned:
//  [0,65536)        W1[512][128]  -> W1t[128][520]
//  [65536,81920)    Wg0[128][128] -> Wg0t[128][136]
//  [81920,98304)    Wg1[128][128] -> Wg1t[128][136]
//  [98304,104448)   W2[128][40]   -> W2t[48][128] (zero-padded cols 40..47)
// ---------------------------------------------------------------------------
__global__ void convert_all_kernel(const float* __restrict__ W1, ushort* __restrict__ W1t,
                                   const float* __restrict__ Wg0, ushort* __restrict__ Wg0t,
                                   const float* __restrict__ Wg1, ushort* __restrict__ Wg1t,
                                   const float* __restrict__ W2, ushort* __restrict__ W2t) {
  int id = blockIdx.x * blockDim.x + threadIdx.x;
  if (id < 65536) {
    int c = id & 127, k = id >> 7;
    W1t[(size_t)c * 520 + k] = f2bf(W1[id]);
  } else if (id < 81920) {
    int t = id - 65536;
    int c = t & 127, k = t >> 7;
    Wg0t[(size_t)c * 136 + k] = f2bf(Wg0[t]);
  } else if (id < 98304) {
    int t = id - 81920;
    int c = t & 127, k = t >> 7;
    Wg1t[(size_t)c * 136 + k] = f2bf(Wg1[t]);
  } else if (id < 104448) {
    int t = id - 98304;
    int c = t >> 7, k = t & 127;
    W2t[(size_t)c * 128 + k] = (c < 40) ? f2bf(W2[(size_t)k * 40 + c]) : (ushort)0;
  }
}

// ---------------------------------------------------------------------------
// B-in-LDS MFMA GEMM: out[M,128](bf16) = A[M,K] @ W. Wt fully staged in LDS.
// AF32 (K=512): depth-1 named-register prefetch, ROLLED x4 unroll (r9-proven).
// r11 lesson: full-unroll + deeper prefetch -> register explosion -> spill.
// ---------------------------------------------------------------------------
template <int K, bool AF32, bool BIAS_RELU, int WAVES>
__global__ __launch_bounds__(WAVES * 64, (WAVES == 16) ? 4 : 16 / WAVES)
void gemm_lds_kernel(
    const void* __restrict__ Ap, const ushort* __restrict__ Wtp,
    const float* __restrict__ bias, ushort* __restrict__ outp,
    int M, int rowsPerBlock) {
  constexpr int KP = K + 8;
  extern __shared__ __align__(16) ushort lB[];  // 128*KP
  const int tid = threadIdx.x;

  const int rowStart = blockIdx.x * rowsPerBlock;
  if (rowStart >= M) return;
  const int rowEnd = min(M, rowStart + rowsPerBlock);

  constexpr int TOTC = 128 * KP / 8;
  const s16x8* Wt8 = (const s16x8*)Wtp;
  for (int i = tid; i < TOTC; i += WAVES * 64) ((s16x8*)lB)[i] = Wt8[i];
  __syncthreads();

  const int w = tid >> 6;
  const int l = tid & 63;
  const int l15 = l & 15;
  const int kg = l >> 4;

  const ushort* Ab = (const ushort*)Ap;
  const float* Af = (const float*)Ap;

  for (int base = rowStart + w * 16; base < rowEnd; base += WAVES * 16) {
    int row = base + l15;
    if (row >= M) row = M - 1;  // clamp loads; stores guarded below

    f32x4 acc[8];
    #pragma unroll
    for (int c = 0; c < 8; ++c) acc[c] = f32x4{0.f, 0.f, 0.f, 0.f};

    if constexpr (AF32) {
      const float* ar = &Af[(size_t)row * K + kg * 8];
      f32x4 p0 = *(const f32x4*)ar;
      f32x4 p1 = *(const f32x4*)(ar + 4);
      #pragma unroll 4
      for (int k0 = 0; k0 < K; k0 += 32) {
        f32x4 c0 = p0, c1 = p1;
        if (k0 + 32 < K) {           // issue next-step loads BEFORE MFMAs
          p0 = *(const f32x4*)(ar + k0 + 32);
          p1 = *(const f32x4*)(ar + k0 + 36);
        }
        uint4 u;
        u.x = pk2bf(c0.x, c0.y);
        u.y = pk2bf(c0.z, c0.w);
        u.z = pk2bf(c1.x, c1.y);
        u.w = pk2bf(c1.z, c1.w);
        s16x8 af = *reinterpret_cast<s16x8*>(&u);
        #pragma unroll
        for (int c = 0; c < 8; ++c) {
          s16x8 bfr = *(const s16x8*)&lB[(16 * c + l15) * KP + k0 + kg * 8];
          acc[c] = __builtin_amdgcn_mfma_f32_16x16x32_bf16(af, bfr, acc[c], 0, 0, 0);
        }
      }
    } else {
      // K=128: preload all A fragments, then pure MFMA+LDS
      s16x8 afs[K / 32];
      #pragma unroll
      for (int k0 = 0; k0 < K; k0 += 32)
        afs[k0 / 32] = *(const s16x8*)&Ab[(size_t)row * K + k0 + kg * 8];
      #pragma unroll
      for (int k0 = 0; k0 < K; k0 += 32) {
        #pragma unroll
        for (int c = 0; c < 8; ++c) {
          s16x8 bfr = *(const s16x8*)&lB[(16 * c + l15) * KP + k0 + kg * 8];
          acc[c] = __builtin_amdgcn_mfma_f32_16x16x32_bf16(afs[k0 / 32], bfr, acc[c], 0, 0, 0);
        }
      }
    }

    #pragma unroll
    for (int c = 0; c < 8; ++c) {
      float b = 0.f;
      if constexpr (BIAS_RELU) b = bias[16 * c + l15];
      #pragma unroll
      for (int v = 0; v < 4; ++v) {
        int r = base + kg * 4 + v;
        if (r < M) {
          float val = acc[c][v];
          if constexpr (BIAS_RELU) val = fmaxf(val + b, 0.f);
          outp[(size_t)r * 128 + 16 * c + l15] = f2bf(val);
        }
      }
    }
  }
}

// ---------------------------------------------------------------------------
// Aggregation over bf16 hw: one wave per node; lane l covers cols 2l,2l+1.
// Packed int2 CSR, unrolled x8 (8 independent 256B gathers in flight).
// ~5.3 TB/s served gather bandwidth = near the fabric/L3 ceiling.
// ---------------------------------------------------------------------------
__global__ __launch_bounds__(256) void aggregate_bf16_kernel(const ushort* __restrict__ hw,
    const int* __restrict__ off, const int2* __restrict__ csr,
    const float* __restrict__ dinv, const float* __restrict__ bias,
    ushort* __restrict__ out, int N) {
  int wid = (blockIdx.x * blockDim.x + threadIdx.x) >> 6;
  int lane = threadIdx.x & 63;
  if (wid >= N) return;
  const uint* hw4 = (const uint*)hw;
  int beg = off[wid], end = off[wid + 1];
  float ax = 0.f, ay = 0.f;
  int j = beg;
  int n8 = beg + ((end - beg) & ~7);
  for (; j < n8; j += 8) {
    int2 c0 = csr[j];     int2 c1 = csr[j + 1];
    int2 c2 = csr[j + 2]; int2 c3 = csr[j + 3];
    int2 c4 = csr[j + 4]; int2 c5 = csr[j + 5];
    int2 c6 = csr[j + 6]; int2 c7 = csr[j + 7];
    uint v0 = hw4[(size_t)c0.x * 64 + lane];
    uint v1 = hw4[(size_t)c1.x * 64 + lane];
    uint v2 = hw4[(size_t)c2.x * 64 + lane];
    uint v3 = hw4[(size_t)c3.x * 64 + lane];
    uint v4 = hw4[(size_t)c4.x * 64 + lane];
    uint v5 = hw4[(size_t)c5.x * 64 + lane];
    uint v6 = hw4[(size_t)c6.x * 64 + lane];
    uint v7 = hw4[(size_t)c7.x * 64 + lane];
    float n0 = __int_as_float(c0.y), n1 = __int_as_float(c1.y);
    float n2 = __int_as_float(c2.y), n3 = __int_as_float(c3.y);
    float n4 = __int_as_float(c4.y), n5 = __int_as_float(c5.y);
    float n6 = __int_as_float(c6.y), n7 = __int_as_float(c7.y);
    ax = fmaf(n0, bf2f_lo(v0), ax); ay = fmaf(n0, bf2f_hi(v0), ay);
    ax = fmaf(n1, bf2f_lo(v1), ax); ay = fmaf(n1, bf2f_hi(v1), ay);
    ax = fmaf(n2, bf2f_lo(v2), ax); ay = fmaf(n2, bf2f_hi(v2), ay);
    ax = fmaf(n3, bf2f_lo(v3), ax); ay = fmaf(n3, bf2f_hi(v3), ay);
    ax = fmaf(n4, bf2f_lo(v4), ax); ay = fmaf(n4, bf2f_hi(v4), ay);
    ax = fmaf(n5, bf2f_lo(v5), ax); ay = fmaf(n5, bf2f_hi(v5), ay);
    ax = fmaf(n6, bf2f_lo(v6), ax); ay = fmaf(n6, bf2f_hi(v6), ay);
    ax = fmaf(n7, bf2f_lo(v7), ax); ay = fmaf(n7, bf2f_hi(v7), ay);
  }
  if (j + 4 <= end) {
    int2 c0 = csr[j];     int2 c1 = csr[j + 1];
    int2 c2 = csr[j + 2]; int2 c3 = csr[j + 3];
    uint v0 = hw4[(size_t)c0.x * 64 + lane];
    uint v1 = hw4[(size_t)c1.x * 64 + lane];
    uint v2 = hw4[(size_t)c2.x * 64 + lane];
    uint v3 = hw4[(size_t)c3.x * 64 + lane];
    float n0 = __int_as_float(c0.y), n1 = __int_as_float(c1.y);
    float n2 = __int_as_float(c2.y), n3 = __int_as_float(c3.y);
    ax = fmaf(n0, bf2f_lo(v0), ax); ay = fmaf(n0, bf2f_hi(v0), ay);
    ax = fmaf(n1, bf2f_lo(v1), ax); ay = fmaf(n1, bf2f_hi(v1), ay);
    ax = fmaf(n2, bf2f_lo(v2), ax); ay = fmaf(n2, bf2f_hi(v2), ay);
    ax = fmaf(n3, bf2f_lo(v3), ax); ay = fmaf(n3, bf2f_hi(v3), ay);
    j += 4;
  }
  for (; j < end; ++j) {
    int2 c = csr[j];
    float nm = __int_as_float(c.y);
    uint v = hw4[(size_t)c.x * 64 + lane];
    ax = fmaf(nm, bf2f_lo(v), ax);
    ay = fmaf(nm, bf2f_hi(v), ay);
  }
  float di = dinv[wid];
  float snm = di * di;
  uint v = hw4[(size_t)wid * 64 + lane];
  ax = fmaf(snm, bf2f_lo(v), ax);
  ay = fmaf(snm, bf2f_hi(v), ay);
  float2 b = ((const float2*)bias)[lane];
  float ox = fmaxf(ax + b.x, 0.f);
  float oy = fmaxf(ay + b.y, 0.f);
  ((uint*)out)[(size_t)wid * 64 + lane] = pk2bf(ox, oy);
}

// ---------------------------------------------------------------------------
// Final: logits = h @ W2 + b2 (MFMA, 48-col padded) ; log_softmax epilogue.
// ---------------------------------------------------------------------------
__global__ __launch_bounds__(256) void final_mfma_kernel(const ushort* __restrict__ h,
    const ushort* __restrict__ W2t, const float* __restrict__ b2,
    float* __restrict__ out, int M) {
  const int tid = threadIdx.x;
  const int w = tid >> 6;
  const int l = tid & 63;
  const int l15 = l & 15;
  const int kg = l >> 4;
  const int base = (blockIdx.x * 4 + w) * 16;
  if (base >= M) return;
  int row = base + l15;
  if (row >= M) row = M - 1;

  f32x4 acc[3];
  #pragma unroll
  for (int c = 0; c < 3; ++c) acc[c] = f32x4{0.f, 0.f, 0.f, 0.f};

  #pragma unroll
  for (int k0 = 0; k0 < 128; k0 += 32) {
    s16x8 af = *(const s16x8*)&h[(size_t)row * 128 + k0 + kg * 8];
    #pragma unroll
    for (int c = 0; c < 3; ++c) {
      s16x8 bfr = *(const s16x8*)&W2t[(size_t)(16 * c + l15) * 128 + k0 + kg * 8];
      acc[c] = __builtin_amdgcn_mfma_f32_16x16x32_bf16(af, bfr, acc[c], 0, 0, 0);
    }
  }

  float bv0 = b2[l15];
  float bv1 = b2[16 + l15];
  float bv2 = (l15 < 8) ? b2[32 + l15] : 0.f;

  #pragma unroll
  for (int v = 0; v < 4; ++v) {
    float l0 = acc[0][v] + bv0;
    float l1 = acc[1][v] + bv1;
    float l2 = (l15 < 8) ? (acc[2][v] + bv2) : -1e30f;
    float pm = fmaxf(fmaxf(l0, l1), l2);
    #pragma unroll
    for (int sh = 8; sh > 0; sh >>= 1) pm = fmaxf(pm, __shfl_xor(pm, sh));
    float es = expf(l0 - pm) + expf(l1 - pm) + ((l15 < 8) ? expf(l2 - pm) : 0.f);
    #pragma unroll
    for (int sh = 8; sh > 0; sh >>= 1) es += __shfl_xor(es, sh);
    float lse = pm + logf(es);
    int r = base + kg * 4 + v;
    if (r < M) {
      out[(size_t)r * 40 + l15] = l0 - lse;
      out[(size_t)r * 40 + 16 + l15] = l1 - lse;
      if (l15 < 8) out[(size_t)r * 40 + 32 + l15] = l2 - lse;
    }
  }
}

// ---------------------------------------------------------------------------
extern "C" void kernel_launch(void* const* d_in, const int* in_sizes, int n_in,
                              void* d_out, int out_size, void* d_ws, size_t ws_size,
                              hipStream_t stream) {
  const float* x   = (const float*)d_in[0];
  const void*  ei  = d_in[1];
  const float* W1  = (const float*)d_in[2];
  const float* b1  = (const float*)d_in[3];
  const float* Wg0 = (const float*)d_in[4];
  const float* bg0 = (const float*)d_in[5];
  const float* Wg1 = (const float*)d_in[6];
  const float* bg1 = (const float*)d_in[7];
  const float* W2  = (const float*)d_in[8];
  const float* b2  = (const float*)d_in[9];
  float* out = (float*)d_out;

  const int N = in_sizes[0] / 512;
  const int E = in_sizes[1] / 2;

  char* wsb = (char*)d_ws;
  size_t o = 0;
  auto alloc = [&](size_t bytes) -> void* {
    void* p = wsb + o;
    o = align_up(o + bytes, 256);
    return p;
  };
  int*    flag    = (int*)alloc(4);
  int*    cnt     = (int*)alloc((size_t)N * 4);
  float*  dinv    = (float*)alloc((size_t)N * 4);
  int*    off     = (int*)alloc((size_t)(N + 1) * 4);
  int*    cursor  = (int*)alloc((size_t)N * 4);
  int*    bsum    = (int*)alloc(128 * 4);
  int*    boff    = (int*)alloc(128 * 4);
  int2*   csr     = (int2*)alloc((size_t)E * 8);
  ushort* W1t     = (ushort*)alloc((size_t)128 * 520 * 2);
  ushort* Wg0t    = (ushort*)alloc((size_t)128 * 136 * 2);
  ushort* Wg1t    = (ushort*)alloc((size_t)128 * 136 * 2);
  ushort* W2t     = (ushort*)alloc((size_t)48 * 128 * 2);
  ushort* hb1     = (ushort*)alloc((size_t)N * HID * 2);
  ushort* hb2     = (ushort*)alloc((size_t)N * HID * 2);
  (void)ws_size; (void)n_in; (void)out_size;

  const int tpb = 256;
  const int ebl = (E + tpb - 1) / tpb;
  const int nbl = (N + tpb - 1) / tpb;

  // --- graph prep ---
  zero_detect_kernel<<<nbl, tpb, 0, stream>>>(cnt, N, (const unsigned int*)ei, 2 * E, flag);
  count_kernel<<<ebl, tpb, 0, stream>>>(ei, flag, E, cnt);
  const int nsb = (N + 1023) / 1024;
  scan_local_kernel<<<nsb, 1024, 0, stream>>>(cnt, off, bsum, dinv, N);
  scan_bsum_kernel<<<1, 128, 0, stream>>>(bsum, nsb, boff, off + N);
  scan_add_kernel<<<nbl, tpb, 0, stream>>>(off, boff, cursor, N);
  fill_kernel<<<ebl, tpb, 0, stream>>>(ei, flag, dinv, cursor, csr, E);

  // --- weight prep (single dispatch) ---
  convert_all_kernel<<<(104448 + 255) / 256, 256, 0, stream>>>(
      W1, W1t, Wg0, Wg0t, Wg1, Wg1t, W2, W2t);

  // --- network ---
  const size_t lds512 = (size_t)128 * 520 * 2;
  const size_t lds128 = (size_t)128 * 136 * 2;
  static bool attr_done = false;
  if (!attr_done) {
    (void)hipFuncSetAttribute(
        reinterpret_cast<const void*>(&gemm_lds_kernel<512, true, true, 16>),
        hipFuncAttributeMaxDynamicSharedMemorySize, (int)lds512);
    attr_done = true;
  }

  int rpb512 = (N + 255) / 256;
  rpb512 = (rpb512 + 15) & ~15;
  const int grid512 = (N + rpb512 - 1) / rpb512;
  const int rpb128 = 128;
  const int grid128 = (N + rpb128 - 1) / rpb128;
  const int abl = (N * 64 + tpb - 1) / tpb;
  const int fbl = (N + 63) / 64;

  gemm_lds_kernel<512, true, true, 16><<<grid512, 1024, lds512, stream>>>(
      x, W1t, b1, hb1, N, rpb512);

  gemm_lds_kernel<128, false, false, 4><<<grid128, 256, lds128, stream>>>(
      hb1, Wg0t, nullptr, hb2, N, rpb128);
  aggregate_bf16_kernel<<<abl, tpb, 0, stream>>>(hb2, off, csr, dinv, bg0, hb1, N);

  gemm_lds_kernel<128, false, false, 4><<<grid128, 256, lds128, stream>>>(
      hb1, Wg1t, nullptr, hb2, N, rpb128);
  aggregate_bf16_kernel<<<abl, tpb, 0, stream>>>(hb2, off, csr, dinv, bg1, hb1, N);

  final_mfma_kernel<<<fbl, 256, 0, stream>>>(hb1, W2t, b2, out, N);
}